// Round 11
// baseline (145.553 us; speedup 1.0000x reference)
//
#include <hip/hip_runtime.h>
#include <math.h>

// Problem constants
#define B_N 2
#define S_N 2048
#define DM  512
#define H_N 8
#define DH  64
#define NC  32     // number of chunks = S/64
#define CH  64     // chunk length

typedef __bf16 bf16x8 __attribute__((ext_vector_type(8)));
typedef float  f32x4  __attribute__((ext_vector_type(4)));

__device__ __forceinline__ unsigned short f2bf(float f) {
    unsigned int u = __float_as_uint(f);
    u += 0x7FFFu + ((u >> 16) & 1u);          // round-to-nearest-even
    return (unsigned short)(u >> 16);
}

// ---------------------------------------------------------------------------
// Kernel 0: fp32 -> bf16 conversion of x, Wqk, Wv, Wo.
// ---------------------------------------------------------------------------
__global__ __launch_bounds__(256) void convert_bf16(
    const float* __restrict__ x,  const float* __restrict__ wqk,
    const float* __restrict__ wv, const float* __restrict__ wo,
    unsigned short* __restrict__ xb,  unsigned short* __restrict__ wqkb,
    unsigned short* __restrict__ wvb, unsigned short* __restrict__ wob)
{
    int gid = blockIdx.x * 256 + threadIdx.x;   // 0..786431 float4 units
    const float* src; unsigned short* dst; int off;
    if (gid < 524288)      { src = x;   dst = xb;   off = gid; }
    else if (gid < 655360) { src = wqk; dst = wqkb; off = gid - 524288; }
    else if (gid < 720896) { src = wv;  dst = wvb;  off = gid - 655360; }
    else                   { src = wo;  dst = wob;  off = gid - 720896; }
    float4 v = ((const float4*)src)[off];
    ushort4 r; r.x = f2bf(v.x); r.y = f2bf(v.y); r.z = f2bf(v.z); r.w = f2bf(v.w);
    ((ushort4*)dst)[off] = r;
}

// ---------------------------------------------------------------------------
// Kernel 1: fused projection + per-chunk state sums.  64-row m-tiles.
// DIRECT global MFMA-fragment loads (no A/B LDS staging, no K-loop barriers):
// per-element reuse within a block is 2 waves -> L1 serves it; L2 traffic
// equals the old global_load_lds scheme.  LDS only for the kv transpose.
// grid = (12, 64):  bx<4 -> q-blocks;  bx>=4 -> kv-blocks (head h=bx-4).
// ---------------------------------------------------------------------------
__global__ __launch_bounds__(256) void gemm_qkv_fused(
    const unsigned short* __restrict__ xb,
    const unsigned short* __restrict__ Wqkb,
    const unsigned short* __restrict__ Wvb,
    const float* __restrict__ bqk, const float* __restrict__ bv,
    unsigned short* __restrict__ qb, unsigned short* __restrict__ kb_,
    unsigned short* __restrict__ vtb,
    float* __restrict__ Asum, float* __restrict__ zsum)
{
    __shared__ unsigned short ktT[64 * 72];   // [d1][t_local] stride 72
    __shared__ unsigned short vtT[64 * 72];   // [d2][t_local]

    const int tid = threadIdx.x;
    const int w = tid >> 6, l = tid & 63;
    const int wm = w >> 1, wn = w & 1;
    const int lane15 = l & 15, quad = l >> 4;
    const int bx = blockIdx.x;
    const int m0 = blockIdx.y * 64;    // grid.y = 64
    const int isq = (bx < 4);
    const int h = isq ? 0 : (bx - 4);

    // row base pointers for this lane's A and B fragment rows
    const unsigned short* arow0 = xb + (size_t)(m0 + wm * 32 + lane15) * DM;        // i=0
    const unsigned short* arow1 = arow0 + 16 * DM;                                   // i=1
    const unsigned short* brow[4];
    #pragma unroll
    for (int j = 0; j < 4; j++) {
        int r = wn * 64 + j * 16 + lane15;        // 0..127 within n-tile
        if (isq)        brow[j] = Wqkb + (size_t)(bx * 128 + r) * DM;
        else if (wn == 0) brow[j] = Wqkb + (size_t)(512 + h * 64 + j * 16 + lane15) * DM;
        else              brow[j] = Wvb  + (size_t)(h * 64 + j * 16 + lane15) * DM;
    }

    f32x4 acc[2][4];
    #pragma unroll
    for (int i = 0; i < 2; i++)
        #pragma unroll
        for (int j = 0; j < 4; j++) acc[i][j] = (f32x4){0.f, 0.f, 0.f, 0.f};

    const int ko = quad * 8;
    #pragma unroll 4
    for (int k0 = 0; k0 < DM; k0 += 32) {
        bf16x8 a0 = *(const bf16x8*)&arow0[k0 + ko];
        bf16x8 a1 = *(const bf16x8*)&arow1[k0 + ko];
        bf16x8 b0 = *(const bf16x8*)&brow[0][k0 + ko];
        bf16x8 b1 = *(const bf16x8*)&brow[1][k0 + ko];
        bf16x8 b2 = *(const bf16x8*)&brow[2][k0 + ko];
        bf16x8 b3 = *(const bf16x8*)&brow[3][k0 + ko];
        acc[0][0] = __builtin_amdgcn_mfma_f32_16x16x32_bf16(a0, b0, acc[0][0], 0, 0, 0);
        acc[0][1] = __builtin_amdgcn_mfma_f32_16x16x32_bf16(a0, b1, acc[0][1], 0, 0, 0);
        acc[0][2] = __builtin_amdgcn_mfma_f32_16x16x32_bf16(a0, b2, acc[0][2], 0, 0, 0);
        acc[0][3] = __builtin_amdgcn_mfma_f32_16x16x32_bf16(a0, b3, acc[0][3], 0, 0, 0);
        acc[1][0] = __builtin_amdgcn_mfma_f32_16x16x32_bf16(a1, b0, acc[1][0], 0, 0, 0);
        acc[1][1] = __builtin_amdgcn_mfma_f32_16x16x32_bf16(a1, b1, acc[1][1], 0, 0, 0);
        acc[1][2] = __builtin_amdgcn_mfma_f32_16x16x32_bf16(a1, b2, acc[1][2], 0, 0, 0);
        acc[1][3] = __builtin_amdgcn_mfma_f32_16x16x32_bf16(a1, b3, acc[1][3], 0, 0, 0);
    }

    const int bbu = m0 >> 11;          // batch index (block-uniform)
    const int t0  = m0 & (S_N - 1);    // global t of local row 0
    const int c0  = t0 >> 6;           // chunk index

    if (isq) {
        #pragma unroll
        for (int i = 0; i < 2; i++) {
            #pragma unroll
            for (int rg = 0; rg < 4; rg++) {
                int m = m0 + wm * 32 + i * 16 + quad * 4 + rg;
                int bb = m >> 11, t = m & (S_N - 1);
                #pragma unroll
                for (int j = 0; j < 4; j++) {
                    int n = bx * 128 + wn * 64 + j * 16 + lane15;   // 0..511
                    float val = acc[i][j][rg] + bqk[n];
                    val = (val > 0.f) ? (val + 1.f) : __expf(val);
                    qb[(((size_t)bb * H_N + (n >> 6)) * S_N + t) * DH + (n & 63)] = f2bf(val);
                }
            }
        }
        return;
    }

    // ---- kv epilogue: wn==0 half is k (elu+1), wn==1 half is v ----
    #pragma unroll
    for (int i = 0; i < 2; i++) {
        #pragma unroll
        for (int rg = 0; rg < 4; rg++) {
            int tl = wm * 32 + i * 16 + quad * 4 + rg;   // local row 0..63
            int t  = t0 + tl;
            #pragma unroll
            for (int j = 0; j < 4; j++) {
                int col = j * 16 + lane15;               // 0..63 within half
                if (wn == 0) {
                    float val = acc[i][j][rg] + bqk[512 + h * 64 + col];
                    val = (val > 0.f) ? (val + 1.f) : __expf(val);
                    unsigned short us = f2bf(val);
                    kb_[(((size_t)bbu * H_N + h) * S_N + t) * DH + col] = us;
                    ktT[col * 72 + tl] = us;
                } else {
                    float val = acc[i][j][rg] + bv[h * 64 + col];
                    vtT[col * 72 + tl] = f2bf(val);
                }
            }
        }
    }
    __syncthreads();

    // ---- coalesced copy vT -> vtb global [bh][d][t] ----
    {
        size_t vbase = (((size_t)bbu * H_N + h) * DH) * S_N + t0;
        #pragma unroll
        for (int it = 0; it < 2; it++) {
            int idx = it * 2048 + tid * 8;
            int d = idx >> 6, tt = idx & 63;
            *(bf16x8*)&vtb[vbase + (size_t)d * S_N + tt] = *(bf16x8*)&vtT[d * 72 + tt];
        }
    }

    // ---- St via MFMA; wave w owns d2 rows 16w..16w+15 ----
    {
        int blk = ((bbu * H_N + h) * NC) + c0;
        bf16x8 va[2];
        #pragma unroll
        for (int s = 0; s < 2; s++)
            va[s] = *(bf16x8*)&vtT[(w * 16 + lane15) * 72 + s * 32 + quad * 8];
        f32x4 sacc[4];
        #pragma unroll
        for (int j = 0; j < 4; j++) sacc[j] = (f32x4){0.f, 0.f, 0.f, 0.f};
        #pragma unroll
        for (int j = 0; j < 4; j++)
            #pragma unroll
            for (int s = 0; s < 2; s++) {
                bf16x8 kB = *(bf16x8*)&ktT[(j * 16 + lane15) * 72 + s * 32 + quad * 8];
                sacc[j] = __builtin_amdgcn_mfma_f32_16x16x32_bf16(va[s], kB, sacc[j], 0, 0, 0);
            }
        #pragma unroll
        for (int j = 0; j < 4; j++)
            #pragma unroll
            for (int rg = 0; rg < 4; rg++)
                Asum[(size_t)blk * 4096 + (w * 16 + quad * 4 + rg) * 64 + j * 16 + lane15] = sacc[j][rg];
    }

    // ---- z: threads 0..63, one d1 each ----
    if (tid < 64) {
        float z = 0.f;
        #pragma unroll
        for (int p = 0; p < 8; p++) {
            bf16x8 kk = *(bf16x8*)&ktT[tid * 72 + p * 8];
            #pragma unroll
            for (int e = 0; e < 8; e++) z += (float)kk[e];
        }
        zsum[(size_t)((bbu * H_N + h) * NC + c0) * 64 + tid] = z;
    }
}

// ---------------------------------------------------------------------------
// Kernel 2: exclusive prefix scan over chunks — register-batched.
// ---------------------------------------------------------------------------
__global__ __launch_bounds__(256) void scan_states(
    const float* __restrict__ Asum, float* __restrict__ zsum,
    unsigned short* __restrict__ Sptb)
{
    const int gid = blockIdx.x * 256 + threadIdx.x;   // 0..66559
    const int bh = gid / 4160;
    const int r  = gid % 4160;
    if (r < 4096) {
        size_t base = (size_t)bh * NC * 4096 + r;
        float vals[NC];
        #pragma unroll
        for (int c = 0; c < NC; c++) vals[c] = Asum[base + (size_t)c * 4096];
        float acc = 0.f;
        #pragma unroll
        for (int c = 0; c < NC; c++) {
            float tmp = vals[c];
            Sptb[base + (size_t)c * 4096] = f2bf(acc);
            acc += tmp;
        }
    } else {
        int d = r - 4096;
        size_t base = (size_t)bh * NC * 64 + d;
        float vals[NC];
        #pragma unroll
        for (int c = 0; c < NC; c++) vals[c] = zsum[base + (size_t)c * 64];
        float acc = 0.f;
        #pragma unroll
        for (int c = 0; c < NC; c++) {
            float tmp = vals[c];
            zsum[base + (size_t)c * 64] = acc;
            acc += tmp;
        }
    }
}

// ---------------------------------------------------------------------------
// Kernel 3: per-chunk attention, all-MFMA (R8-proven version).
// ---------------------------------------------------------------------------
__global__ __launch_bounds__(256) void attn_mfma(
    const unsigned short* __restrict__ qb, const unsigned short* __restrict__ kb_,
    const unsigned short* __restrict__ vtb, const unsigned short* __restrict__ Sptb,
    const float* __restrict__ zsum, unsigned short* __restrict__ ctxb)
{
    __shared__ __align__(16) unsigned short P[64 * 72];
    __shared__ float nupart[64][4];

    const int blk = blockIdx.x;           // 0..511
    const int bh = blk >> 5, c = blk & 31;
    const int b = bh >> 3, h = bh & 7;
    const int tid = threadIdx.x;
    const int w = tid >> 6, l = tid & 63;
    const int lane15 = l & 15, quad = l >> 4;

    const unsigned short* qc  = qb  + (size_t)bh * S_N * DH + c * CH * DH;  // [t][d]
    const unsigned short* kc  = kb_ + (size_t)bh * S_N * DH + c * CH * DH;  // [u][d]
    const unsigned short* vtc = vtb + (size_t)bh * DH * S_N + c * CH;       // [d2][t], stride S_N
    const unsigned short* spc = Sptb + (size_t)blk * 4096;                  // [d2][d1]
    const float* zc = zsum + (size_t)blk * 64;

    bf16x8 af[2];
    #pragma unroll
    for (int s = 0; s < 2; s++)
        af[s] = *(const bf16x8*)&qc[(w * 16 + lane15) * DH + s * 32 + quad * 8];

    // scores S[t][u]
    f32x4 sacc[4];
    #pragma unroll
    for (int j = 0; j < 4; j++) sacc[j] = (f32x4){0.f, 0.f, 0.f, 0.f};
    #pragma unroll
    for (int j = 0; j < 4; j++)
        #pragma unroll
        for (int s = 0; s < 2; s++) {
            bf16x8 bk = *(const bf16x8*)&kc[(j * 16 + lane15) * DH + s * 32 + quad * 8];
            sacc[j] = __builtin_amdgcn_mfma_f32_16x16x32_bf16(af[s], bk, sacc[j], 0, 0, 0);
        }

    // causal mask + store P (bf16) to LDS
    const int r0 = w * 16 + quad * 4;
    #pragma unroll
    for (int j = 0; j < 4; j++) {
        int u = j * 16 + lane15;
        #pragma unroll
        for (int rg = 0; rg < 4; rg++) {
            int rr = r0 + rg;
            float v = (u <= rr) ? sacc[j][rg] : 0.f;
            P[rr * 72 + u] = f2bf(v);
        }
    }
    __syncthreads();

    // nu: thread (tl, part) sums P[tl][16*part..+15] + q.zprev strip
    const int tl = tid >> 2, part = tid & 3;
    float nup = 0.f;
    {
        bf16x8 p0 = *(const bf16x8*)&P[tl * 72 + part * 16];
        bf16x8 p1 = *(const bf16x8*)&P[tl * 72 + part * 16 + 8];
        bf16x8 q0 = *(const bf16x8*)&qc[tl * DH + part * 16];
        bf16x8 q1 = *(const bf16x8*)&qc[tl * DH + part * 16 + 8];
        #pragma unroll
        for (int i = 0; i < 8; i++) {
            nup += (float)p0[i] + (float)p1[i];
            nup += (float)q0[i] * zc[part * 16 + i];
            nup += (float)q1[i] * zc[part * 16 + 8 + i];
        }
    }
    nupart[tl][part] = nup;
    __syncthreads();

    // numerator: intra (P @ vt) + inter (q @ Spt), fused accumulator
    bf16x8 pa[2];
    #pragma unroll
    for (int s = 0; s < 2; s++)
        pa[s] = *(const bf16x8*)&P[(w * 16 + lane15) * 72 + s * 32 + quad * 8];

    f32x4 acc[4];
    #pragma unroll
    for (int j = 0; j < 4; j++) acc[j] = (f32x4){0.f, 0.f, 0.f, 0.f};
    #pragma unroll
    for (int j = 0; j < 4; j++)
        #pragma unroll
        for (int s = 0; s < 2; s++) {
            bf16x8 bv8 = *(const bf16x8*)&vtc[(size_t)(j * 16 + lane15) * S_N + s * 32 + quad * 8];
            acc[j] = __builtin_amdgcn_mfma_f32_16x16x32_bf16(pa[s], bv8, acc[j], 0, 0, 0);
            bf16x8 bs = *(const bf16x8*)&spc[(j * 16 + lane15) * 64 + s * 32 + quad * 8];
            acc[j] = __builtin_amdgcn_mfma_f32_16x16x32_bf16(af[s], bs, acc[j], 0, 0, 0);
        }

    // epilogue: divide by nu, write ctx bf16 [b*S+t][DM]
    #pragma unroll
    for (int rg = 0; rg < 4; rg++) {
        int rr = r0 + rg;
        float nu = nupart[rr][0] + nupart[rr][1] + nupart[rr][2] + nupart[rr][3];
        float inv = 1.f / nu;
        size_t obase = ((size_t)b * S_N + c * CH + rr) * DM + h * DH;
        #pragma unroll
        for (int j = 0; j < 4; j++)
            ctxb[obase + j * 16 + lane15] = f2bf(acc[j][rg] * inv);
    }
}

// ---------------------------------------------------------------------------
// Kernel 4: output projection, DIRECT global fragment loads (no LDS, no
// barriers).  64x64 tiles, grid (8,64).
// ---------------------------------------------------------------------------
__global__ __launch_bounds__(256) void gemm_out_mfma(
    const unsigned short* __restrict__ ctxb,
    const unsigned short* __restrict__ Wob,
    const float* __restrict__ bo, float* __restrict__ out)
{
    const int tid = threadIdx.x;
    const int w = tid >> 6, l = tid & 63;
    const int wm = w >> 1, wn = w & 1;
    const int lane15 = l & 15, quad = l >> 4;
    const int n0 = blockIdx.x * 64;    // grid.x = 8
    const int m0 = blockIdx.y * 64;    // grid.y = 64

    const unsigned short* arow0 = ctxb + (size_t)(m0 + wm * 32 + lane15) * DM;
    const unsigned short* arow1 = arow0 + 16 * DM;
    const unsigned short* brow0 = Wob + (size_t)(n0 + wn * 32 + lane15) * DM;
    const unsigned short* brow1 = brow0 + 16 * DM;

    f32x4 acc[2][2];
    #pragma unroll
    for (int i = 0; i < 2; i++)
        #pragma unroll
        for (int j = 0; j < 2; j++) acc[i][j] = (f32x4){0.f, 0.f, 0.f, 0.f};

    const int ko = quad * 8;
    #pragma unroll 4
    for (int k0 = 0; k0 < DM; k0 += 32) {
        bf16x8 a0 = *(const bf16x8*)&arow0[k0 + ko];
        bf16x8 a1 = *(const bf16x8*)&arow1[k0 + ko];
        bf16x8 b0 = *(const bf16x8*)&brow0[k0 + ko];
        bf16x8 b1 = *(const bf16x8*)&brow1[k0 + ko];
        acc[0][0] = __builtin_amdgcn_mfma_f32_16x16x32_bf16(a0, b0, acc[0][0], 0, 0, 0);
        acc[0][1] = __builtin_amdgcn_mfma_f32_16x16x32_bf16(a0, b1, acc[0][1], 0, 0, 0);
        acc[1][0] = __builtin_amdgcn_mfma_f32_16x16x32_bf16(a1, b0, acc[1][0], 0, 0, 0);
        acc[1][1] = __builtin_amdgcn_mfma_f32_16x16x32_bf16(a1, b1, acc[1][1], 0, 0, 0);
    }

    #pragma unroll
    for (int i = 0; i < 2; i++) {
        #pragma unroll
        for (int rg = 0; rg < 4; rg++) {
            int m = m0 + wm * 32 + i * 16 + quad * 4 + rg;
            #pragma unroll
            for (int j = 0; j < 2; j++) {
                int n = n0 + wn * 32 + j * 16 + lane15;
                out[(size_t)m * DM + n] = acc[i][j][rg] + bo[n];
            }
        }
    }
}

// ---------------------------------------------------------------------------
extern "C" void kernel_launch(void* const* d_in, const int* in_sizes, int n_in,
                              void* d_out, int out_size, void* d_ws, size_t ws_size,
                              hipStream_t stream)
{
    const float* x   = (const float*)d_in[0];
    const float* Wqk = (const float*)d_in[1];
    const float* bqk = (const float*)d_in[2];
    const float* Wv  = (const float*)d_in[3];
    const float* bv  = (const float*)d_in[4];
    const float* Wo  = (const float*)d_in[5];
    const float* bo  = (const float*)d_in[6];
    float* out = (float*)d_out;

    const size_t NTOK = (size_t)B_N * S_N * DM;   // 2,097,152
    float* Asum = (float*)d_ws;                   // NTOK fp32
    float* zsum = Asum + NTOK;                    // 32768 fp32
    unsigned short* xb   = (unsigned short*)(zsum + 32768);
    unsigned short* Wqkb = xb   + NTOK;
    unsigned short* Wvb  = Wqkb + 524288;
    unsigned short* Wob  = Wvb  + 262144;
    unsigned short* qb   = Wob  + 262144;
    unsigned short* kb_  = qb   + NTOK;
    unsigned short* vtb  = kb_  + NTOK;
    unsigned short* Sptb = vtb  + NTOK;
    unsigned short* ctxb = Sptb + NTOK;

    convert_bf16  <<<dim3(3072),   256, 0, stream>>>(x, Wqk, Wv, Wo, xb, Wqkb, Wvb, Wob);
    gemm_qkv_fused<<<dim3(12, 64), 256, 0, stream>>>(xb, Wqkb, Wvb, bqk, bv, qb, kb_, vtb, Asum, zsum);
    scan_states   <<<dim3(260),    256, 0, stream>>>(Asum, zsum, Sptb);
    attn_mfma     <<<dim3(512),    256, 0, stream>>>(qb, kb_, vtb, Sptb, zsum, ctxb);
    gemm_out_mfma <<<dim3(8, 64),  256, 0, stream>>>(ctxb, Wob, bo, out);
}